// Round 2
// baseline (337.616 us; speedup 1.0000x reference)
//
#include <hip/hip_runtime.h>

// Output = conv1x1(x, refine_w, refine_b). Everything else in the reference is
// dead code: `_dead` is unused, and x_back == x exactly (permutation followed
// by its argsort-inverse).
//
// x: (8, 64, 256, 256) fp32, refine_w: (64, 64) [o-major], refine_b: (64,)
// out[b,o,h,w] = sum_c w[o,c] * x[b,c,h,w] + b[o]
//
// R1 lesson: float2 acc[64] (128 VGPRs) forced compiler loop-fission
// (VGPR_Count=72, re-read of x, 22% occupancy, 116 us). This version: 1 pixel
// per thread -> acc[64] = 64 VGPRs, no fission, 2048 blocks.

constexpr int  C    = 64;
constexpr long HW   = 65536;      // 256*256
constexpr long NPIX = 8L * HW;    // 524288 pixels total

__global__ __launch_bounds__(256, 4) void conv1x1_refine_kernel(
    const float* __restrict__ x,
    const float* __restrict__ w,     // (64,64) o-major
    const float* __restrict__ bias,  // (64,)
    float* __restrict__ out)
{
    const long tid = (long)blockIdx.x * blockDim.x + threadIdx.x; // one pixel
    const long b   = tid >> 16;            // pixel / HW
    const long hw  = tid & (HW - 1);       // pixel % HW

    const float* xp = x   + b * (C * HW) + hw;
    float*       op = out + b * (C * HW) + hw;

    float acc[C];
#pragma unroll
    for (int o = 0; o < C; ++o) acc[o] = bias[o];  // uniform -> s_load

#pragma unroll 4
    for (int c = 0; c < C; ++c) {
        const float xv = xp[(long)c * HW];         // coalesced 256 B/wave
#pragma unroll
        for (int o = 0; o < C; ++o) {
            // w[] address is grid-uniform -> scalar load, SGPR operand of v_fmac
            acc[o] = fmaf(w[o * C + c], xv, acc[o]);
        }
    }

#pragma unroll
    for (int o = 0; o < C; ++o) {
        // streaming store: don't evict x from L3 (x may be re-read while the
        // write stream passes through once and is never re-read)
        __builtin_nontemporal_store(acc[o], op + (long)o * HW);
    }
}

extern "C" void kernel_launch(void* const* d_in, const int* in_sizes, int n_in,
                              void* d_out, int out_size, void* d_ws, size_t ws_size,
                              hipStream_t stream)
{
    const float* x  = (const float*)d_in[0];   // x
    const float* rw = (const float*)d_in[11];  // refine_w
    const float* rb = (const float*)d_in[12];  // refine_b
    float* out = (float*)d_out;

    const int threads = 256;
    const int blocks  = (int)(NPIX / threads); // 2048
    hipLaunchKernelGGL(conv1x1_refine_kernel, dim3(blocks), dim3(threads), 0, stream,
                       x, rw, rb, out);
}

// Round 3
// 289.184 us; speedup vs baseline: 1.1675x; 1.1675x over previous
//
#include <hip/hip_runtime.h>

// Output = conv1x1(x, refine_w, refine_b). Everything else in the reference is
// dead code: `_dead` is unused, and x_back == x exactly (permutation followed
// by its argsort-inverse).
//
// x: (8, 64, 256, 256) fp32, refine_w: (64, 64) [o-major], refine_b: (64,)
// out[b,o,h,w] = sum_c w[o,c] * x[b,c,h,w] + b[o]
//
// R1/R2 lesson: any per-thread ACCUMULATOR ARRAY over o gets loop-fissioned by
// the compiler (VGPR_Count 72/44, x re-read per chunk, 4x VALU inflation).
// This version inverts the loops: stage all 64 input channels in registers
// (xv[64], loads hoisted & un-fissionable since every o uses all of xv), then
// each o is a self-contained dot product -> scalar acc -> immediate store.

constexpr int  C    = 64;
constexpr long HW   = 65536;      // 256*256
constexpr long NPIX = 8L * HW;    // 524288 pixels total

__global__ __launch_bounds__(256, 4) void conv1x1_refine_kernel(
    const float* __restrict__ x,
    const float* __restrict__ w,     // (64,64) o-major
    const float* __restrict__ bias,  // (64,)
    float* __restrict__ out)
{
    const long tid = (long)blockIdx.x * blockDim.x + threadIdx.x; // one pixel
    const long b   = tid >> 16;            // pixel / HW
    const long hw  = tid & (HW - 1);       // pixel % HW

    const float* xp = x   + b * (C * HW) + hw;
    float*       op = out + b * (C * HW) + hw;

    // Stage the whole input-channel column in registers. 64 independent
    // coalesced dword loads (256 B/wave each) issued back-to-back -> ~16 KB
    // of memory-level parallelism per wave.
    float xv[C];
#pragma unroll
    for (int c = 0; c < C; ++c) xv[c] = xp[(long)c * HW];

    // One output channel at a time: scalar accumulator, immediate store.
    // unroll 4 -> 4 independent FMA chains to hide the 4-cyc dep latency.
#pragma unroll 4
    for (int o = 0; o < C; ++o) {
        float s = bias[o];                 // uniform -> s_load
#pragma unroll
        for (int c = 0; c < C; ++c) {
            // w address uniform -> SGPR operand of v_fmac
            s = fmaf(w[o * C + c], xv[c], s);
        }
        __builtin_nontemporal_store(s, op + (long)o * HW);
    }
}

extern "C" void kernel_launch(void* const* d_in, const int* in_sizes, int n_in,
                              void* d_out, int out_size, void* d_ws, size_t ws_size,
                              hipStream_t stream)
{
    const float* x  = (const float*)d_in[0];   // x
    const float* rw = (const float*)d_in[11];  // refine_w
    const float* rb = (const float*)d_in[12];  // refine_b
    float* out = (float*)d_out;

    const int threads = 256;
    const int blocks  = (int)(NPIX / threads); // 2048
    hipLaunchKernelGGL(conv1x1_refine_kernel, dim3(blocks), dim3(threads), 0, stream,
                       x, rw, rb, out);
}